// Round 9
// baseline (34.298 us; speedup 1.0000x reference)
//
#include <hip/hip_runtime.h>
#include <hip/hip_bf16.h>

// Problem constants (fixed by setup_inputs):
//   x: (64, 8192) f32   weight: (8192, 2048) f32
//   random_numbers: (4,) int (int32 or int64 storage, values in [1, 2^20))
//   y: (64, 8192) f32
#define K_FULL   8192
#define M_ROWS   64
#define N_OUT    8192
#define N_COMP   2048
#define P_MERS   2147483647

// ws layout: [0, 256KB) : xcF bf16, fragment-major:
//   xcF[((s*4 + g)*64 + lane)*8 + e] = xc[g*16 + (lane&15)][s*32 + (lane>>4)*8 + e]
//   (s = k-step 0..63, g = m-group 0..3) -> every A-fragment load is 64x16B contiguous.

typedef __attribute__((ext_vector_type(8))) short bf16x8;
typedef __attribute__((ext_vector_type(4))) float f32x4;

__device__ __forceinline__ short f2bfs(float f) {
    __hip_bfloat16 h = __float2bfloat16(f);
    return *reinterpret_cast<short*>(&h);
}

__device__ __forceinline__ int hash_col(int j, int rn0, int rn1, int rn2, int rn3) {
    if (rn1 == 0 && rn3 == 0) {
        // int64 storage (JAX x64 on): exact hash; Mersenne fold (2^31 === 1 mod P)
        unsigned long long xx = (unsigned long long)(unsigned int)rn0 * (unsigned int)j
                              + (unsigned long long)(unsigned int)rn2;
        unsigned long long t = (xx & (unsigned long long)P_MERS) + (xx >> 31);
        if (t >= (unsigned long long)P_MERS) t -= (unsigned long long)P_MERS;
        return (int)(t & (N_COMP - 1));
    } else {
        // int32 storage (JAX x64 off): int32 wraparound + floored mod
        unsigned int t = (unsigned int)rn0 * (unsigned int)j + (unsigned int)rn1;
        int ti = (int)t;
        int m1 = ti % P_MERS;
        if (m1 < 0) m1 += P_MERS;
        return m1 & (N_COMP - 1);
    }
}

// Fused scatter+pack: block = one m row. LDS scatter-add, then pack bf16 into
// fragment-major xcF (scattered dword writes, 4KB/block -> negligible).
__global__ __launch_bounds__(1024) void k_xc(const float* __restrict__ x,
                                             const int* __restrict__ rn,
                                             unsigned int* __restrict__ xcF) {
    __shared__ float row[N_COMP];
    const int m = blockIdx.x;
    const int tid = threadIdx.x;
    row[tid] = 0.0f;
    row[tid + 1024] = 0.0f;
    const int rn0 = rn[0], rn1 = rn[1], rn2 = rn[2], rn3 = rn[3];
    __syncthreads();

    const float* xm = x + (size_t)m * K_FULL;
#pragma unroll
    for (int it = 0; it < 2; ++it) {
        int j0 = tid * 4 + it * 4096;
        float4 v = *(const float4*)(xm + j0);
        atomicAdd(&row[hash_col(j0 + 0, rn0, rn1, rn2, rn3)], v.x);
        atomicAdd(&row[hash_col(j0 + 1, rn0, rn1, rn2, rn3)], v.y);
        atomicAdd(&row[hash_col(j0 + 2, rn0, rn1, rn2, rn3)], v.z);
        atomicAdd(&row[hash_col(j0 + 3, rn0, rn1, rn2, rn3)], v.w);
    }
    __syncthreads();

    // pack c0=2*tid, c0+1 (same s,kg; adjacent e -> one dword)
    const int c0 = 2 * tid;
    const int s  = c0 >> 5;
    const int kg = (c0 >> 3) & 3;
    const int e0 = c0 & 7;
    const int g  = m >> 4;
    const int nr = m & 15;
    unsigned int pk = (unsigned int)(unsigned short)f2bfs(row[c0])
                    | ((unsigned int)(unsigned short)f2bfs(row[c0 + 1]) << 16);
    xcF[(((s * 4 + g) * 64 + kg * 16 + nr) << 2) + (e0 >> 1)] = pk;
}

// MFMA GEMM v5: block = 16 n-cols x all 2048 k, 512 thr (8 waves).
// No LDS staging, no k-loop barriers. Wave w computes k-steps s = t*8 + w
// (t = 0..7): B-fragment loaded DIRECTLY from row-major W (16 rows x 64-128B
// contiguous per load -> full granule utilization), converted f32->bf16 in
// register; A-fragments from fragment-major xcF (64x16B contiguous, L2-hot).
// Interleaved step assignment keeps the block's 8 waves sweeping each W row
// near-sequentially. 2-deep manual pipeline; single barrier + LDS reduce of
// the 8 wave-partials at the end; coalesced stores, no atomics.
__global__ __launch_bounds__(512) void k_gemm(const float* __restrict__ W,
                                              const unsigned short* __restrict__ xcF,
                                              float* __restrict__ y) {
    __shared__ float ys[8][M_ROWS][16];          // 32 KB (only LDS use)
    const int tid  = threadIdx.x;
    const int lane = tid & 63;
    const int w    = __builtin_amdgcn_readfirstlane(tid >> 6);  // wave 0..7
    const int nr   = lane & 15;
    const int kg   = lane >> 4;
    const int n0   = blockIdx.x * 16;

    // B pointer: row n0+nr, k-offset (t*8+w)*32 + kg*8  (f32)
    const float* wp = W + (size_t)(n0 + nr) * N_COMP + w * 32 + kg * 8;
    // A pointer: xcF shorts offset ((s*4+g)*64 + lane)*8, s = t*8+w
    const unsigned short* ap = xcF + (size_t)w * 2048 + lane * 8;

    f32x4 acc0 = {0.f, 0.f, 0.f, 0.f};
    f32x4 acc1 = {0.f, 0.f, 0.f, 0.f};
    f32x4 acc2 = {0.f, 0.f, 0.f, 0.f};
    f32x4 acc3 = {0.f, 0.f, 0.f, 0.f};

#define LOADW(W0, W1, T) do { int o_ = (T) * 256;                      \
        (W0) = *(const float4*)(wp + o_);                              \
        (W1) = *(const float4*)(wp + o_ + 4); } while (0)
#define LOADA(A0, A1, A2, A3, T) do {                                  \
        const unsigned short* p_ = ap + (size_t)(T) * 16384;           \
        (A0) = *(const bf16x8*)(p_);                                   \
        (A1) = *(const bf16x8*)(p_ + 512);                             \
        (A2) = *(const bf16x8*)(p_ + 1024);                            \
        (A3) = *(const bf16x8*)(p_ + 1536); } while (0)
#define DOMFMA(W0, W1, A0, A1, A2, A3) do { bf16x8 b_;                 \
        b_[0] = f2bfs((W0).x); b_[1] = f2bfs((W0).y);                  \
        b_[2] = f2bfs((W0).z); b_[3] = f2bfs((W0).w);                  \
        b_[4] = f2bfs((W1).x); b_[5] = f2bfs((W1).y);                  \
        b_[6] = f2bfs((W1).z); b_[7] = f2bfs((W1).w);                  \
        acc0 = __builtin_amdgcn_mfma_f32_16x16x32_bf16((A0), b_, acc0, 0, 0, 0); \
        acc1 = __builtin_amdgcn_mfma_f32_16x16x32_bf16((A1), b_, acc1, 0, 0, 0); \
        acc2 = __builtin_amdgcn_mfma_f32_16x16x32_bf16((A2), b_, acc2, 0, 0, 0); \
        acc3 = __builtin_amdgcn_mfma_f32_16x16x32_bf16((A3), b_, acc3, 0, 0, 0); } while (0)

    float4 wa0, wa1, wb0, wb1;
    bf16x8 aa0, aa1, aa2, aa3, ab0, ab1, ab2, ab3;

    LOADW(wa0, wa1, 0);
    LOADA(aa0, aa1, aa2, aa3, 0);
#pragma unroll 1
    for (int t = 0; t < 6; t += 2) {
        LOADW(wb0, wb1, t + 1);
        LOADA(ab0, ab1, ab2, ab3, t + 1);
        DOMFMA(wa0, wa1, aa0, aa1, aa2, aa3);
        LOADW(wa0, wa1, t + 2);
        LOADA(aa0, aa1, aa2, aa3, t + 2);
        DOMFMA(wb0, wb1, ab0, ab1, ab2, ab3);
    }
    LOADW(wb0, wb1, 7);
    LOADA(ab0, ab1, ab2, ab3, 7);
    DOMFMA(wa0, wa1, aa0, aa1, aa2, aa3);
    DOMFMA(wb0, wb1, ab0, ab1, ab2, ab3);

    // C/D layout (m89-verified): col = lane&15, row = (lane>>4)*4 + j
#pragma unroll
    for (int j = 0; j < 4; ++j) {
        ys[w][ 0 + kg * 4 + j][nr] = acc0[j];
        ys[w][16 + kg * 4 + j][nr] = acc1[j];
        ys[w][32 + kg * 4 + j][nr] = acc2[j];
        ys[w][48 + kg * 4 + j][nr] = acc3[j];
    }
    __syncthreads();

    // reduce 8 wave-partials, direct store: 1024 outputs, 2 per thread
#pragma unroll
    for (int i = 0; i < 2; ++i) {
        int o = tid + 512 * i;
        int m = o >> 4;
        int n = o & 15;
        float s = 0.f;
#pragma unroll
        for (int q = 0; q < 8; ++q) s += ys[q][m][n];
        y[(size_t)m * N_OUT + n0 + n] = s;
    }
}

extern "C" void kernel_launch(void* const* d_in, const int* in_sizes, int n_in,
                              void* d_out, int out_size, void* d_ws, size_t ws_size,
                              hipStream_t stream) {
    const float* x = (const float*)d_in[0];
    const float* W = (const float*)d_in[1];
    const int* rn  = (const int*)d_in[2];
    float* y       = (float*)d_out;

    unsigned int* xcF = (unsigned int*)d_ws;

    k_xc<<<M_ROWS, 1024, 0, stream>>>(x, rn, xcF);
    k_gemm<<<N_OUT / 16, 512, 0, stream>>>(W, (const unsigned short*)xcF, y);
}